// Round 1
// baseline (279.727 us; speedup 1.0000x reference)
//
#include <hip/hip_runtime.h>

// CCE loss reduction: out[0] = -sum(input * log(target + 1e-8)) / B
// B = 262144, C = 128, f32 inputs. Pure streaming reduction, HBM-bound.
// 268 MB total read -> ~43 us floor at 6.3 TB/s achievable.

constexpr int BLOCK = 256;

__global__ __launch_bounds__(BLOCK) void cce_reduce_kernel(
    const float* __restrict__ inp, const float* __restrict__ tgt,
    float* __restrict__ out, int n4, float neg_inv_b) {
  const float4* __restrict__ in4 = reinterpret_cast<const float4*>(inp);
  const float4* __restrict__ tg4 = reinterpret_cast<const float4*>(tgt);

  int idx = blockIdx.x * BLOCK + threadIdx.x;
  int stride = gridDim.x * BLOCK;

  float acc = 0.0f;
  for (int i = idx; i < n4; i += stride) {
    float4 x = in4[i];
    float4 y = tg4[i];
    acc += x.x * __logf(y.x + 1e-8f);
    acc += x.y * __logf(y.y + 1e-8f);
    acc += x.z * __logf(y.z + 1e-8f);
    acc += x.w * __logf(y.w + 1e-8f);
  }

  // wave-64 shuffle reduction
  #pragma unroll
  for (int off = 32; off > 0; off >>= 1)
    acc += __shfl_down(acc, off, 64);

  __shared__ float s[BLOCK / 64];
  int lane = threadIdx.x & 63;
  int wave = threadIdx.x >> 6;
  if (lane == 0) s[wave] = acc;
  __syncthreads();

  if (threadIdx.x == 0) {
    float t = 0.0f;
    #pragma unroll
    for (int w = 0; w < BLOCK / 64; ++w) t += s[w];
    atomicAdd(out, t * neg_inv_b);  // one device-scope atomic per block
  }
}

extern "C" void kernel_launch(void* const* d_in, const int* in_sizes, int n_in,
                              void* d_out, int out_size, void* d_ws, size_t ws_size,
                              hipStream_t stream) {
  const float* inp = reinterpret_cast<const float*>(d_in[0]);
  const float* tgt = reinterpret_cast<const float*>(d_in[1]);
  float* out = reinterpret_cast<float*>(d_out);

  const long long n = (long long)in_sizes[0];  // 262144 * 128
  const int n4 = (int)(n / 4);                 // exactly divisible (128 cols)
  const long long B = 262144;                  // rows, per reference
  const float neg_inv_b = -1.0f / (float)B;

  // d_out is re-poisoned to 0xAA before every timed launch -> zero it here.
  hipMemsetAsync(d_out, 0, out_size * sizeof(float), stream);

  // 2048 blocks = 8 blocks/CU across 256 CUs; grid-stride covers 8.4M float4s.
  const int grid = 2048;
  cce_reduce_kernel<<<grid, BLOCK, 0, stream>>>(inp, tgt, out, n4, neg_inv_b);
}

// Round 2
// 278.840 us; speedup vs baseline: 1.0032x; 1.0032x over previous
//
#include <hip/hip_runtime.h>

// CCE loss reduction: out[0] = -sum(input * log(target + 1e-8)) / B
// B = 262144, C = 128, f32 inputs. Streaming reduction, memory-bound.
// R1 was latency-bound (VGPR=12, 2 outstanding loads/wave, 2.6 TB/s eff).
// R2: 4x manual unroll -> 8 loads in flight/wave, 2 acc chains.

constexpr int BLOCK = 256;
constexpr int GRID  = 2048;  // 8 blocks/CU x 256 CUs; all 8192 waves resident

__global__ __launch_bounds__(BLOCK) void cce_reduce_kernel(
    const float* __restrict__ inp, const float* __restrict__ tgt,
    float* __restrict__ out, int n4, float neg_inv_b) {
  const float4* __restrict__ in4 = reinterpret_cast<const float4*>(inp);
  const float4* __restrict__ tg4 = reinterpret_cast<const float4*>(tgt);

  const int idx    = blockIdx.x * BLOCK + threadIdx.x;
  const int stride = GRID * BLOCK;

  float acc0 = 0.0f, acc1 = 0.0f;

  int i = idx;
  // Main loop: 4 iterations batched -> 8 independent dwordx4 loads in flight.
  for (; i + 3 * stride < n4; i += 4 * stride) {
    float4 x0 = in4[i];
    float4 y0 = tg4[i];
    float4 x1 = in4[i + stride];
    float4 y1 = tg4[i + stride];
    float4 x2 = in4[i + 2 * stride];
    float4 y2 = tg4[i + 2 * stride];
    float4 x3 = in4[i + 3 * stride];
    float4 y3 = tg4[i + 3 * stride];

    acc0 += x0.x * __logf(y0.x + 1e-8f);
    acc1 += x0.y * __logf(y0.y + 1e-8f);
    acc0 += x0.z * __logf(y0.z + 1e-8f);
    acc1 += x0.w * __logf(y0.w + 1e-8f);
    acc0 += x1.x * __logf(y1.x + 1e-8f);
    acc1 += x1.y * __logf(y1.y + 1e-8f);
    acc0 += x1.z * __logf(y1.z + 1e-8f);
    acc1 += x1.w * __logf(y1.w + 1e-8f);
    acc0 += x2.x * __logf(y2.x + 1e-8f);
    acc1 += x2.y * __logf(y2.y + 1e-8f);
    acc0 += x2.z * __logf(y2.z + 1e-8f);
    acc1 += x2.w * __logf(y2.w + 1e-8f);
    acc0 += x3.x * __logf(y3.x + 1e-8f);
    acc1 += x3.y * __logf(y3.y + 1e-8f);
    acc0 += x3.z * __logf(y3.z + 1e-8f);
    acc1 += x3.w * __logf(y3.w + 1e-8f);
  }
  // Tail (not taken for 262144x128, but keep it general).
  for (; i < n4; i += stride) {
    float4 x = in4[i];
    float4 y = tg4[i];
    acc0 += x.x * __logf(y.x + 1e-8f);
    acc1 += x.y * __logf(y.y + 1e-8f);
    acc0 += x.z * __logf(y.z + 1e-8f);
    acc1 += x.w * __logf(y.w + 1e-8f);
  }

  float acc = acc0 + acc1;

  // wave-64 shuffle reduction
  #pragma unroll
  for (int off = 32; off > 0; off >>= 1)
    acc += __shfl_down(acc, off, 64);

  __shared__ float s[BLOCK / 64];
  const int lane = threadIdx.x & 63;
  const int wave = threadIdx.x >> 6;
  if (lane == 0) s[wave] = acc;
  __syncthreads();

  if (threadIdx.x == 0) {
    float t = 0.0f;
    #pragma unroll
    for (int w = 0; w < BLOCK / 64; ++w) t += s[w];
    atomicAdd(out, t * neg_inv_b);  // one device-scope atomic per block
  }
}

extern "C" void kernel_launch(void* const* d_in, const int* in_sizes, int n_in,
                              void* d_out, int out_size, void* d_ws, size_t ws_size,
                              hipStream_t stream) {
  const float* inp = reinterpret_cast<const float*>(d_in[0]);
  const float* tgt = reinterpret_cast<const float*>(d_in[1]);
  float* out = reinterpret_cast<float*>(d_out);

  const long long n = (long long)in_sizes[0];  // 262144 * 128
  const int n4 = (int)(n / 4);                 // exactly divisible (128 cols)
  const long long B = 262144;                  // rows, per reference
  const float neg_inv_b = -1.0f / (float)B;

  // d_out is re-poisoned to 0xAA before every timed launch -> zero it here.
  hipMemsetAsync(d_out, 0, out_size * sizeof(float), stream);

  cce_reduce_kernel<<<GRID, BLOCK, 0, stream>>>(inp, tgt, out, n4, neg_inv_b);
}